// Round 1
// baseline (20.405 us; speedup 1.0000x reference)
//
#include <hip/hip_runtime.h>

// Problem constants (match reference)
constexpr int Bc = 128;
constexpr int Nc = 256;
constexpr int Hc = 272;
constexpr int Wc = 152;
constexpr int RMAXc = 8;

// One 64-lane wave per object. All lanes compute the per-object scalar params
// redundantly (same-address loads broadcast; no shuffles needed), then lanes
// stride the (2r+1)^2 gaussian window doing atomicMax into the heatmap.
__global__ __launch_bounds__(256) void draw_gaussian_kernel(
    const float* __restrict__ flow,   // [B,2,H,W]
    const float* __restrict__ wh,     // [B,N,4]
    const int*   __restrict__ mask,   // [B,N]
    const int*   __restrict__ index,  // [B,N]
    float*       __restrict__ hm)     // [B,H,W] (pre-zeroed)
{
    const int gid  = blockIdx.x * blockDim.x + threadIdx.x;
    const int obj  = gid >> 6;            // one wave per object
    const int lane = threadIdx.x & 63;
    if (obj >= Bc * Nc) return;
    const int b = obj / Nc;

    if (mask[obj] == 0) return;           // pred*0 -> x=y=w=h=0 -> invalid

    const int idx = index[obj];           // in [0, H*W)
    const float x = flow[(b * 2 + 0) * (Hc * Wc) + idx];
    const float y = flow[(b * 2 + 1) * (Hc * Wc) + idx];

    const float4 whv = *reinterpret_cast<const float4*>(wh + obj * 4);
    const float w = whv.x + whv.z;
    const float h = whv.y + whv.w;

    // valid = (h>0)&(w>0)&(x>0)&(y>0)&(x<152)&(y<272)
    if (!(h > 0.0f && w > 0.0f && x > 0.0f && y > 0.0f &&
          x < 152.0f && y < 272.0f)) return;

    // gaussian_radius(ceil(h), ceil(w)), f32 op order mirroring the reference
    const float height = ceilf(h);
    const float width  = ceilf(w);

    const float b1  = height + width;
    const float c1  = width * height * 0.3f / 1.7f;        // *(1-ov)/(1+ov)
    const float sq1 = sqrtf(b1 * b1 - 4.0f * c1);
    const float r1  = (b1 + sq1) * 0.5f;

    const float b2  = 2.0f * (height + width);
    const float c2  = 0.3f * width * height;               // (1-ov)*w*h
    const float sq2 = sqrtf(b2 * b2 - 16.0f * c2);
    const float r2  = (b2 + sq2) * 0.5f;

    const float b3  = -1.4f * (height + width);            // -2*ov*(h+w)
    const float c3  = -0.3f * width * height;              // (ov-1)*w*h
    const float sq3 = sqrtf(b3 * b3 - 11.2f * c3);         // -16*ov*c3
    const float r3  = (b3 + sq3) * 0.5f;

    float radius = fminf(fminf(r1, r2), r3);
    radius = fmaxf(radius, 0.0f);
    if (!(radius >= 0.0f)) return;        // NaN guard (matches: NaN comparisons false)

    const float rf = floorf(radius);      // integer-valued float
    int ri = (int)rf;
    if (ri > RMAXc) ri = RMAXc;           // reference window is limited to [-8,8]

    const float sigma = (2.0f * rf + 1.0f) / 6.0f;
    const float denom = 2.0f * sigma * sigma;

    const int xi = (int)floorf(x);
    const int yi = (int)floorf(y);

    const int dw    = 2 * ri + 1;
    const int total = dw * dw;

    for (int c = lane; c < total; c += 64) {
        const int dy = c / dw - ri;
        const int dx = c % dw - ri;
        const int yy = yi + dy;
        const int xx = xi + dx;
        if (yy < 0 || yy >= Hc || xx < 0 || xx >= Wc) continue;

        const float dist2 = (float)(dx * dx + dy * dy);
        const float g = expf(-dist2 / denom);
        if (g < 2e-15f) continue;         // reference zeroes these; max(0) is a no-op

        // All values are >= 0, so int-punned atomicMax == float max.
        atomicMax(reinterpret_cast<int*>(&hm[(b * Hc + yy) * Wc + xx]),
                  __float_as_int(g));
    }
}

extern "C" void kernel_launch(void* const* d_in, const int* in_sizes, int n_in,
                              void* d_out, int out_size, void* d_ws, size_t ws_size,
                              hipStream_t stream) {
    const float* flow  = (const float*)d_in[0];  // [B,2,H,W] f32
    const float* wh    = (const float*)d_in[1];  // [B,N,4]   f32
    const int*   mask  = (const int*)d_in[2];    // [B,N]     i32
    const int*   index = (const int*)d_in[3];    // [B,N]     i32
    float* hm = (float*)d_out;                   // [B,1,H,W] f32

    // Zero the heatmap every call (harness poisons once, never re-poisons).
    hipMemsetAsync(hm, 0, (size_t)out_size * sizeof(float), stream);

    // One wave per object, 4 waves per 256-thread block.
    const int objs   = Bc * Nc;                  // 32768
    const int waves_per_block = 256 / 64;
    const int blocks = objs / waves_per_block;   // 8192
    draw_gaussian_kernel<<<blocks, 256, 0, stream>>>(flow, wh, mask, index, hm);
}

// Round 2
// 20.319 us; speedup vs baseline: 1.0042x; 1.0042x over previous
//
#include <hip/hip_runtime.h>

// Problem constants (match reference)
constexpr int Bc = 128;
constexpr int Nc = 256;
constexpr int Hc = 272;
constexpr int Wc = 152;
constexpr int RMAXc = 8;

// Vectorized zero-fill: 16B per lane, grid-stride. Replaces rocclr's
// fillBufferAligned which only hit 508 GB/s on this 21 MB buffer.
__global__ __launch_bounds__(256) void zero_kernel(float4* __restrict__ out, int n4) {
    int i = blockIdx.x * blockDim.x + threadIdx.x;
    const int stride = gridDim.x * blockDim.x;
    const float4 z = make_float4(0.f, 0.f, 0.f, 0.f);
    for (; i < n4; i += stride) out[i] = z;
}

// One 64-lane wave per object. All lanes compute the per-object scalar params
// redundantly (same-address loads broadcast; no shuffles needed), then lanes
// stride the (2r+1)^2 gaussian window doing atomicMax into the heatmap.
__global__ __launch_bounds__(256) void draw_gaussian_kernel(
    const float* __restrict__ flow,   // [B,2,H,W]
    const float* __restrict__ wh,     // [B,N,4]
    const int*   __restrict__ mask,   // [B,N]
    const int*   __restrict__ index,  // [B,N]
    float*       __restrict__ hm)     // [B,H,W] (pre-zeroed)
{
    const int gid  = blockIdx.x * blockDim.x + threadIdx.x;
    const int obj  = gid >> 6;            // one wave per object
    const int lane = threadIdx.x & 63;
    if (obj >= Bc * Nc) return;
    const int b = obj / Nc;

    if (mask[obj] == 0) return;           // pred*0 -> x=y=w=h=0 -> invalid

    const int idx = index[obj];           // in [0, H*W)
    const float x = flow[(b * 2 + 0) * (Hc * Wc) + idx];
    const float y = flow[(b * 2 + 1) * (Hc * Wc) + idx];

    const float4 whv = *reinterpret_cast<const float4*>(wh + obj * 4);
    const float w = whv.x + whv.z;
    const float h = whv.y + whv.w;

    // valid = (h>0)&(w>0)&(x>0)&(y>0)&(x<152)&(y<272)
    if (!(h > 0.0f && w > 0.0f && x > 0.0f && y > 0.0f &&
          x < 152.0f && y < 272.0f)) return;

    // gaussian_radius(ceil(h), ceil(w)), f32 op order mirroring the reference
    const float height = ceilf(h);
    const float width  = ceilf(w);

    const float b1  = height + width;
    const float c1  = width * height * 0.3f / 1.7f;        // *(1-ov)/(1+ov)
    const float sq1 = sqrtf(b1 * b1 - 4.0f * c1);
    const float r1  = (b1 + sq1) * 0.5f;

    const float b2  = 2.0f * (height + width);
    const float c2  = 0.3f * width * height;               // (1-ov)*w*h
    const float sq2 = sqrtf(b2 * b2 - 16.0f * c2);
    const float r2  = (b2 + sq2) * 0.5f;

    const float b3  = -1.4f * (height + width);            // -2*ov*(h+w)
    const float c3  = -0.3f * width * height;              // (ov-1)*w*h
    const float sq3 = sqrtf(b3 * b3 - 11.2f * c3);         // -16*ov*c3
    const float r3  = (b3 + sq3) * 0.5f;

    float radius = fminf(fminf(r1, r2), r3);
    radius = fmaxf(radius, 0.0f);
    if (!(radius >= 0.0f)) return;        // NaN guard (matches: NaN comparisons false)

    const float rf = floorf(radius);      // integer-valued float
    int ri = (int)rf;
    if (ri > RMAXc) ri = RMAXc;           // reference window is limited to [-8,8]

    const float sigma = (2.0f * rf + 1.0f) / 6.0f;
    const float denom = 2.0f * sigma * sigma;

    const int xi = (int)floorf(x);
    const int yi = (int)floorf(y);

    const int dw    = 2 * ri + 1;
    const int total = dw * dw;

    for (int c = lane; c < total; c += 64) {
        const int dy = c / dw - ri;
        const int dx = c % dw - ri;
        const int yy = yi + dy;
        const int xx = xi + dx;
        if (yy < 0 || yy >= Hc || xx < 0 || xx >= Wc) continue;

        const float dist2 = (float)(dx * dx + dy * dy);
        const float g = expf(-dist2 / denom);
        if (g < 2e-15f) continue;         // reference zeroes these; max(0) is a no-op

        // All values are >= 0, so int-punned atomicMax == float max.
        atomicMax(reinterpret_cast<int*>(&hm[(b * Hc + yy) * Wc + xx]),
                  __float_as_int(g));
    }
}

extern "C" void kernel_launch(void* const* d_in, const int* in_sizes, int n_in,
                              void* d_out, int out_size, void* d_ws, size_t ws_size,
                              hipStream_t stream) {
    const float* flow  = (const float*)d_in[0];  // [B,2,H,W] f32
    const float* wh    = (const float*)d_in[1];  // [B,N,4]   f32
    const int*   mask  = (const int*)d_in[2];    // [B,N]     i32
    const int*   index = (const int*)d_in[3];    // [B,N]     i32
    float* hm = (float*)d_out;                   // [B,1,H,W] f32

    // Zero the heatmap every call (harness poisons once, never re-poisons).
    // out_size = 128*272*152 = 5,292,032 floats, divisible by 4.
    const int n4 = out_size / 4;
    zero_kernel<<<2048, 256, 0, stream>>>((float4*)hm, n4);

    // One wave per object, 4 waves per 256-thread block.
    const int objs   = Bc * Nc;                  // 32768
    const int waves_per_block = 256 / 64;
    const int blocks = objs / waves_per_block;   // 8192
    draw_gaussian_kernel<<<blocks, 256, 0, stream>>>(flow, wh, mask, index, hm);
}